// Round 3
// baseline (1013.529 us; speedup 1.0000x reference)
//
#include <hip/hip_runtime.h>
#include <hip/hip_bf16.h>

#define TDIM 2048
#define BDIM 32
#define NDIM 1024
#define N2DIM 512
#define BN (BDIM * NDIM)   // 32768
#define LDSP 72            // padded LDS row stride in shorts (144 B, 16B-aligned)

typedef float f32x4 __attribute__((ext_vector_type(4)));
typedef __bf16 bf16x8 __attribute__((ext_vector_type(8)));

__device__ __forceinline__ float bf2f(unsigned int u) {
    union { unsigned int i; float f; } c;
    c.i = (u & 0xffffu) << 16;
    return c.f;
}

__device__ __forceinline__ unsigned short f2bf(float f) {
    union { float f; unsigned int i; } c;
    c.f = f;
    unsigned int i = c.i;
    unsigned int r = (i >> 16) & 1u;
    i += 0x7fffu + r;          // round-to-nearest-even
    return (unsigned short)(i >> 16);
}

// Runtime dtype detector. W_b ~ U(-1/32, 1/32): as bf16 ALL of its first 64
// uint16s have (u&0x7fff) <= 0x3D00 (|v| <= 2^-5). As fp32, even-index
// uint16s are mantissa bits (uniform) -> count < 64 w.p. 1 - 5e-11.
__device__ __forceinline__ int detect_f32(const void* wb) {
    const unsigned short* p = (const unsigned short*)wb;
    int cnt = 0;
    #pragma unroll
    for (int i = 0; i < 64; ++i) cnt += ((p[i] & 0x7fffu) <= 0x3D00u) ? 1 : 0;
    return cnt != 64;
}

// load element i of a float tensor stored as either fp32 or bf16
__device__ __forceinline__ float ldf(const void* p, size_t i, int isf32) {
    if (isf32) return ((const float*)p)[i];
    return bf2f(((const unsigned short*)p)[i]);
}

__device__ __forceinline__ float tanh_fast(float x) {
    float e = __expf(2.0f * x);
    return 1.0f - 2.0f / (e + 1.0f);
}

// ---------------------------------------------------------------------------
// Kernel 1: column mean over T. grid 128, block 256; thread per (b,n) column.
// Wave reads 64 consecutive elements per t -> coalesced.
// ---------------------------------------------------------------------------
__global__ __launch_bounds__(256) void k_mean(const void* __restrict__ hyp,
                                              const void* __restrict__ wb,
                                              float* __restrict__ m) {
    const int isf32 = detect_f32(wb);
    int i = blockIdx.x * 256 + threadIdx.x;        // 0..32767
    float s = 0.f;
    if (isf32) {
        const float* h = (const float*)hyp;
        #pragma unroll 8
        for (int t = 0; t < TDIM; ++t) s += h[(size_t)t * BN + i];
    } else {
        const unsigned short* h = (const unsigned short*)hyp;
        #pragma unroll 8
        for (int t = 0; t < TDIM; ++t) s += bf2f(h[(size_t)t * BN + i]);
    }
    m[i] = s * (1.0f / (float)TDIM);
}

// ---------------------------------------------------------------------------
// Kernel 2: g[b][k] = tanh(m[b]·Wm_w[k] + Wm_b[k]) * Wh_w[k]
// one wave per output; grid 4096, block 256 (4 waves)
// ---------------------------------------------------------------------------
__global__ __launch_bounds__(256) void k_g(const float* __restrict__ m,
                                           const void* __restrict__ Wm_w,
                                           const void* __restrict__ Wm_b,
                                           const void* __restrict__ Wh_w,
                                           const void* __restrict__ wb,
                                           float* __restrict__ g) {
    const int isf32 = detect_f32(wb);
    int wid  = (blockIdx.x * 256 + threadIdx.x) >> 6;  // 0..16383
    int lane = threadIdx.x & 63;
    int b = wid >> 9;
    int k = wid & 511;
    const float* mr = m + (size_t)b * NDIM;
    float s = 0.f;
    for (int i = lane; i < NDIM; i += 64)
        s += mr[i] * ldf(Wm_w, (size_t)k * NDIM + i, isf32);
    #pragma unroll
    for (int off = 32; off > 0; off >>= 1) s += __shfl_down(s, off, 64);
    if (lane == 0) {
        float v = tanh_fast(s + ldf(Wm_b, k, isf32));
        g[(size_t)b * N2DIM + k] = v * ldf(Wh_w, k, isf32);
    }
}

// ---------------------------------------------------------------------------
// Kernel 3: fused GEMM+tanh+weighted-k-reduce producing score[b][t].
// Block tile [128 t x 128 kcol]; kblk loop covers 512 kcols. Plain padded
// LDS staging; fp32 inputs are converted to bf16 during staging.
// grid (16, 32) = (t-tiles, b), block 256 (4 waves, 2x2).
// ---------------------------------------------------------------------------
__global__ __launch_bounds__(256) void k_score(const void* __restrict__ hyp,
                                               const void* __restrict__ W_w,
                                               const void* __restrict__ W_b,
                                               const float* __restrict__ g,
                                               float* __restrict__ score) {
    __shared__ __align__(16) unsigned short sA[128 * LDSP];  // 18 KB
    __shared__ __align__(16) unsigned short sW[128 * LDSP];  // 18 KB
    __shared__ float sRed[2][128];

    const int isf32 = detect_f32(W_b);
    const int tid = threadIdx.x;
    const int l   = tid & 63;
    const int w   = tid >> 6;        // wave 0..3
    const int wt  = w & 1;           // t half (64 rows)
    const int wkk = w >> 1;          // kcol half (64 rows of W)
    const int lm  = l & 15;
    const int lq  = l >> 4;
    const int b   = blockIdx.y;
    const int t0  = blockIdx.x * 128;

    float scoreAcc[4][4];
    #pragma unroll
    for (int mi = 0; mi < 4; ++mi)
        #pragma unroll
        for (int r = 0; r < 4; ++r) scoreAcc[mi][r] = 0.f;

    for (int kblk = 0; kblk < 4; ++kblk) {
        f32x4 acc[4][4];
        #pragma unroll
        for (int mi = 0; mi < 4; ++mi)
            #pragma unroll
            for (int ni = 0; ni < 4; ++ni) {
                f32x4 z = {0.f, 0.f, 0.f, 0.f};
                acc[mi][ni] = z;
            }

        for (int it = 0; it < 16; ++it) {
            const int n0 = it * 64;
            // stage A tile [128 t x 64 n] and W tile [128 k x 64 n]
            // chunk ch = p*256+tid: row = ch>>3, 8-elem pos = ch&7
            #pragma unroll
            for (int p = 0; p < 4; ++p) {
                int ch  = p * 256 + tid;
                int row = ch >> 3;
                int pos = ch & 7;
                size_t offA = (size_t)(t0 + row) * BN + b * NDIM + n0 + pos * 8;
                size_t offW = (size_t)(kblk * 128 + row) * NDIM + n0 + pos * 8;
                uint4 va, vw;
                if (isf32) {
                    const float4* fa = (const float4*)((const float*)hyp + offA);
                    float4 a0 = fa[0], a1 = fa[1];
                    va.x = f2bf(a0.x) | ((unsigned)f2bf(a0.y) << 16);
                    va.y = f2bf(a0.z) | ((unsigned)f2bf(a0.w) << 16);
                    va.z = f2bf(a1.x) | ((unsigned)f2bf(a1.y) << 16);
                    va.w = f2bf(a1.z) | ((unsigned)f2bf(a1.w) << 16);
                    const float4* fw = (const float4*)((const float*)W_w + offW);
                    float4 w0 = fw[0], w1 = fw[1];
                    vw.x = f2bf(w0.x) | ((unsigned)f2bf(w0.y) << 16);
                    vw.y = f2bf(w0.z) | ((unsigned)f2bf(w0.w) << 16);
                    vw.z = f2bf(w1.x) | ((unsigned)f2bf(w1.y) << 16);
                    vw.w = f2bf(w1.z) | ((unsigned)f2bf(w1.w) << 16);
                } else {
                    va = *(const uint4*)((const unsigned short*)hyp + offA);
                    vw = *(const uint4*)((const unsigned short*)W_w + offW);
                }
                *(uint4*)&sA[row * LDSP + pos * 8] = va;
                *(uint4*)&sW[row * LDSP + pos * 8] = vw;
            }
            __syncthreads();

            #pragma unroll
            for (int kk = 0; kk < 2; ++kk) {
                const int koff = kk * 32 + lq * 8;
                bf16x8 af[4];
                #pragma unroll
                for (int mi = 0; mi < 4; ++mi) {
                    int mrow = wt * 64 + mi * 16 + lm;
                    af[mi] = *(const bf16x8*)&sA[mrow * LDSP + koff];
                }
                #pragma unroll
                for (int ni = 0; ni < 4; ++ni) {
                    int nrow = wkk * 64 + ni * 16 + lm;
                    bf16x8 bfr = *(const bf16x8*)&sW[nrow * LDSP + koff];
                    #pragma unroll
                    for (int mi = 0; mi < 4; ++mi)
                        acc[mi][ni] = __builtin_amdgcn_mfma_f32_16x16x32_bf16(
                            af[mi], bfr, acc[mi][ni], 0, 0, 0);
                }
            }
            __syncthreads();   // protect LDS before next staging round
        }

        // epilogue: tanh + fold g, accumulate per-t partial scores in regs
        // D layout: col(lane&15)=kcol(B free dim), row(lq*4+r)=t(A free dim)
        #pragma unroll
        for (int ni = 0; ni < 4; ++ni) {
            int kc = kblk * 128 + wkk * 64 + ni * 16 + lm;
            float wbv = ldf(W_b, kc, isf32);
            float gg  = g[(size_t)b * N2DIM + kc];
            #pragma unroll
            for (int mi = 0; mi < 4; ++mi)
                #pragma unroll
                for (int r = 0; r < 4; ++r) {
                    float v = tanh_fast(acc[mi][ni][r] + wbv);
                    scoreAcc[mi][r] += v * gg;
                }
        }
    }

    // reduce across the 16 kcol-lanes, then across the 2 wkk waves via LDS
    #pragma unroll
    for (int mi = 0; mi < 4; ++mi)
        #pragma unroll
        for (int r = 0; r < 4; ++r) {
            float s = scoreAcc[mi][r];
            s += __shfl_xor(s, 1, 64);
            s += __shfl_xor(s, 2, 64);
            s += __shfl_xor(s, 4, 64);
            s += __shfl_xor(s, 8, 64);
            if (lm == 0) sRed[wkk][wt * 64 + mi * 16 + lq * 4 + r] = s;
        }
    __syncthreads();
    if (tid < 128) {
        score[(size_t)b * TDIM + t0 + tid] = sRed[0][tid] + sRed[1][tid];
    }
}

// ---------------------------------------------------------------------------
// Kernel 4: softmax over T per batch. grid 32, block 256 (8 elems/thread).
// ---------------------------------------------------------------------------
__global__ __launch_bounds__(256) void k_softmax(const float* __restrict__ score,
                                                 float* __restrict__ a) {
    __shared__ float red[8];
    int b = blockIdx.x;
    int tid = threadIdx.x;
    int w = tid >> 6, l = tid & 63;
    const float* s = score + (size_t)b * TDIM;
    float v[8];
    float mx = -1e30f;
    #pragma unroll
    for (int i = 0; i < 8; ++i) { v[i] = s[tid + i * 256]; mx = fmaxf(mx, v[i]); }
    #pragma unroll
    for (int off = 32; off > 0; off >>= 1) mx = fmaxf(mx, __shfl_xor(mx, off, 64));
    if (l == 0) red[w] = mx;
    __syncthreads();
    mx = fmaxf(fmaxf(red[0], red[1]), fmaxf(red[2], red[3]));
    float sum = 0.f;
    #pragma unroll
    for (int i = 0; i < 8; ++i) { v[i] = __expf(v[i] - mx); sum += v[i]; }
    #pragma unroll
    for (int off = 32; off > 0; off >>= 1) sum += __shfl_xor(sum, off, 64);
    if (l == 0) red[4 + w] = sum;
    __syncthreads();
    sum = red[4] + red[5] + red[6] + red[7];
    float inv = 1.0f / sum;
    float* ap = a + (size_t)b * TDIM;
    #pragma unroll
    for (int i = 0; i < 8; ++i) ap[tid + i * 256] = v[i] * inv;
}

// ---------------------------------------------------------------------------
// Kernel 5: c[b][n] = sum_t a[b][t]*hyp[t][b*N+n], written straight to out
// in the detected dtype. grid 128, block 256; thread per column.
// ---------------------------------------------------------------------------
__global__ __launch_bounds__(256) void k_wsum_out(const void* __restrict__ hyp,
                                                  const float* __restrict__ a,
                                                  const void* __restrict__ wb,
                                                  void* __restrict__ out) {
    const int isf32 = detect_f32(wb);
    int i = blockIdx.x * 256 + threadIdx.x;        // 0..32767
    int b = i >> 10;
    const float* av = a + (size_t)b * TDIM;
    float s = 0.f;
    if (isf32) {
        const float* h = (const float*)hyp;
        #pragma unroll 8
        for (int t = 0; t < TDIM; ++t) s += av[t] * h[(size_t)t * BN + i];
    } else {
        const unsigned short* h = (const unsigned short*)hyp;
        #pragma unroll 8
        for (int t = 0; t < TDIM; ++t) s += av[t] * bf2f(h[(size_t)t * BN + i]);
    }
    if (isf32) ((float*)out)[i] = s;
    else       ((unsigned short*)out)[i] = f2bf(s);
}

extern "C" void kernel_launch(void* const* d_in, const int* in_sizes, int n_in,
                              void* d_out, int out_size, void* d_ws, size_t ws_size,
                              hipStream_t stream) {
    const void* hyp  = d_in[0];
    const void* W_w  = d_in[1];
    const void* W_b  = d_in[2];
    const void* Wm_w = d_in[3];
    const void* Wm_b = d_in[4];
    const void* Wh_w = d_in[5];
    // d_in[6] (Wh_b) is softmax-invariant -> unused.

    float* ws    = (float*)d_ws;
    float* m     = ws;                       // 32768 floats
    float* g     = m + BN;                   // 16384
    float* score = g + BDIM * N2DIM;         // 65536
    float* a     = score + BDIM * TDIM;      // 65536  (total 704 KB)

    k_mean    <<<dim3(128),   256, 0, stream>>>(hyp, W_b, m);
    k_g       <<<dim3(4096),  256, 0, stream>>>(m, Wm_w, Wm_b, Wh_w, W_b, g);
    k_score   <<<dim3(16, 32),256, 0, stream>>>(hyp, W_w, W_b, g, score);
    k_softmax <<<dim3(32),    256, 0, stream>>>(score, a);
    k_wsum_out<<<dim3(128),   256, 0, stream>>>(hyp, a, W_b, d_out);
}

// Round 4
// 564.137 us; speedup vs baseline: 1.7966x; 1.7966x over previous
//
#include <hip/hip_runtime.h>
#include <hip/hip_bf16.h>

#define TDIM 2048
#define BDIM 32
#define NDIM 1024
#define N2DIM 512
#define BN (BDIM * NDIM)   // 32768
#define LDSP 72            // fallback padded LDS row stride (shorts)

typedef float f32x4 __attribute__((ext_vector_type(4)));
typedef __bf16 bf16x8 __attribute__((ext_vector_type(8)));

__device__ __forceinline__ float bf2f(unsigned int u) {
    union { unsigned int i; float f; } c;
    c.i = (u & 0xffffu) << 16;
    return c.f;
}

__device__ __forceinline__ unsigned short f2bf(float f) {
    union { float f; unsigned int i; } c;
    c.f = f;
    unsigned int i = c.i;
    unsigned int r = (i >> 16) & 1u;
    i += 0x7fffu + r;          // round-to-nearest-even
    return (unsigned short)(i >> 16);
}

// Runtime dtype detector (evidence says fp32, but keep the guard).
__device__ __forceinline__ int detect_f32(const void* wb) {
    const unsigned short* p = (const unsigned short*)wb;
    int cnt = 0;
    #pragma unroll
    for (int i = 0; i < 64; ++i) cnt += ((p[i] & 0x7fffu) <= 0x3D00u) ? 1 : 0;
    return cnt != 64;
}

__device__ __forceinline__ float ldf(const void* p, size_t i, int isf32) {
    if (isf32) return ((const float*)p)[i];
    return bf2f(((const unsigned short*)p)[i]);
}

__device__ __forceinline__ float tanh_fast(float x) {
    float e = __expf(2.0f * x);
    return 1.0f - 2.0f / (e + 1.0f);
}

__device__ __forceinline__ void unpack8(uint4 u, float* f) {
    f[0] = bf2f(u.x); f[1] = bf2f(u.x >> 16);
    f[2] = bf2f(u.y); f[3] = bf2f(u.y >> 16);
    f[4] = bf2f(u.z); f[5] = bf2f(u.z >> 16);
    f[6] = bf2f(u.w); f[7] = bf2f(u.w >> 16);
}

__device__ __forceinline__ void async16(const void* g, void* l) {
    __builtin_amdgcn_global_load_lds(
        (const __attribute__((address_space(1))) void*)g,
        (__attribute__((address_space(3))) void*)l, 16, 0, 0);
}

// ===========================================================================
// PRIMARY PATH (needs ws >= 138,084,352 B)
// ===========================================================================

// ---------------------------------------------------------------------------
// P1: partial column sums + bf16 conversion of hyp. grid (32,16), block 256.
// Thread owns 4 cols; loops 128 t of chunk tc. part[tc][col] = partial sum.
// ---------------------------------------------------------------------------
__global__ __launch_bounds__(256) void k_mean_cvt(const void* __restrict__ hyp,
                                                  const void* __restrict__ wb,
                                                  unsigned short* __restrict__ hyp16,
                                                  float* __restrict__ part) {
    const int isf32 = detect_f32(wb);
    const int col4 = (blockIdx.x * 256 + threadIdx.x) * 4;
    const int tc   = blockIdx.y;
    float a0 = 0.f, a1 = 0.f, a2 = 0.f, a3 = 0.f;
    if (isf32) {
        const float* h = (const float*)hyp + (size_t)(tc * 128) * BN + col4;
        unsigned short* o = hyp16 + (size_t)(tc * 128) * BN + col4;
        #pragma unroll 4
        for (int tt = 0; tt < 128; ++tt) {
            float4 v = *(const float4*)(h + (size_t)tt * BN);
            a0 += v.x; a1 += v.y; a2 += v.z; a3 += v.w;
            ushort4 u = { f2bf(v.x), f2bf(v.y), f2bf(v.z), f2bf(v.w) };
            *(ushort4*)(o + (size_t)tt * BN) = u;
        }
    } else {
        const unsigned short* h = (const unsigned short*)hyp + (size_t)(tc * 128) * BN + col4;
        unsigned short* o = hyp16 + (size_t)(tc * 128) * BN + col4;
        #pragma unroll 4
        for (int tt = 0; tt < 128; ++tt) {
            ushort4 u = *(const ushort4*)(h + (size_t)tt * BN);
            *(ushort4*)(o + (size_t)tt * BN) = u;
            a0 += bf2f(u.x); a1 += bf2f(u.y); a2 += bf2f(u.z); a3 += bf2f(u.w);
        }
    }
    float4 r = { a0, a1, a2, a3 };
    *(float4*)(part + (size_t)tc * BN + col4) = r;
}

// P2: reduce 16 partials -> mean. grid 32, block 256 (4 cols/thread).
__global__ __launch_bounds__(256) void k_reduce_mean(const float* __restrict__ part,
                                                     float* __restrict__ m) {
    int i4 = (blockIdx.x * 256 + threadIdx.x) * 4;
    float4 s = { 0.f, 0.f, 0.f, 0.f };
    #pragma unroll
    for (int c = 0; c < 16; ++c) {
        float4 v = *(const float4*)(part + (size_t)c * BN + i4);
        s.x += v.x; s.y += v.y; s.z += v.z; s.w += v.w;
    }
    float k = 1.0f / (float)TDIM;
    float4 r = { s.x * k, s.y * k, s.z * k, s.w * k };
    *(float4*)(m + i4) = r;
}

// P3: convert W_w -> bf16. grid 512, block 256 (4 elems/thread).
__global__ __launch_bounds__(256) void k_cvtW(const void* __restrict__ W_w,
                                              const void* __restrict__ wb,
                                              unsigned short* __restrict__ W16) {
    const int isf32 = detect_f32(wb);
    int i4 = (blockIdx.x * 256 + threadIdx.x) * 4;
    if (isf32) {
        float4 v = *(const float4*)((const float*)W_w + i4);
        ushort4 u = { f2bf(v.x), f2bf(v.y), f2bf(v.z), f2bf(v.w) };
        *(ushort4*)(W16 + i4) = u;
    } else {
        *(ushort4*)(W16 + i4) = *(const ushort4*)((const unsigned short*)W_w + i4);
    }
}

// Shared: g[b][k] = tanh(m[b]·Wm_w[k] + Wm_b[k]) * Wh_w[k]. grid 4096, blk 256.
__global__ __launch_bounds__(256) void k_g(const float* __restrict__ m,
                                           const void* __restrict__ Wm_w,
                                           const void* __restrict__ Wm_b,
                                           const void* __restrict__ Wh_w,
                                           const void* __restrict__ wb,
                                           float* __restrict__ g) {
    const int isf32 = detect_f32(wb);
    int wid  = (blockIdx.x * 256 + threadIdx.x) >> 6;
    int lane = threadIdx.x & 63;
    int b = wid >> 9;
    int k = wid & 511;
    const float* mr = m + (size_t)b * NDIM;
    float s = 0.f;
    for (int i = lane; i < NDIM; i += 64)
        s += mr[i] * ldf(Wm_w, (size_t)k * NDIM + i, isf32);
    #pragma unroll
    for (int off = 32; off > 0; off >>= 1) s += __shfl_down(s, off, 64);
    if (lane == 0) {
        float v = tanh_fast(s + ldf(Wm_b, k, isf32));
        g[(size_t)b * N2DIM + k] = v * ldf(Wh_w, k, isf32);
    }
}

// ---------------------------------------------------------------------------
// P4: fused GEMM+tanh+weighted-k-reduce on bf16 inputs via global_load_lds.
// Tile [128 t x 128 kcol], 4 waves 2x2. XOR-swizzled frag-order LDS:
// chunk (row,pos) holds content column-chunk kq = pos ^ (row&7).
// grid (16, 32), block 256.
// ---------------------------------------------------------------------------
__global__ __launch_bounds__(256) void k_score(const unsigned short* __restrict__ hyp16,
                                               const unsigned short* __restrict__ W16,
                                               const void* __restrict__ W_b,
                                               const float* __restrict__ g,
                                               float* __restrict__ score) {
    __shared__ __align__(16) unsigned short sA[128 * 64];  // 16 KB
    __shared__ __align__(16) unsigned short sW[128 * 64];  // 16 KB
    __shared__ float sRed[2][128];

    const int isf32 = detect_f32(W_b);
    const int tid = threadIdx.x;
    const int l   = tid & 63;
    const int w   = tid >> 6;
    const int wt  = w & 1;
    const int wkk = w >> 1;
    const int lm  = l & 15;
    const int lq  = l >> 4;
    const int b   = blockIdx.y;
    const int t0  = blockIdx.x * 128;

    const int grow = l >> 3;                 // row within 8-row group
    const int gkq  = (l & 7) ^ grow;         // global 16B-chunk column
    const int swz0 = ((lq)     ^ (lm & 7)) * 8;
    const int swz1 = ((4 + lq) ^ (lm & 7)) * 8;

    float scoreAcc[4][4];
    #pragma unroll
    for (int mi = 0; mi < 4; ++mi)
        #pragma unroll
        for (int r = 0; r < 4; ++r) scoreAcc[mi][r] = 0.f;

    for (int kblk = 0; kblk < 4; ++kblk) {
        f32x4 acc[4][4];
        #pragma unroll
        for (int mi = 0; mi < 4; ++mi)
            #pragma unroll
            for (int ni = 0; ni < 4; ++ni) {
                f32x4 z = {0.f, 0.f, 0.f, 0.f};
                acc[mi][ni] = z;
            }

        for (int it = 0; it < 16; ++it) {
            const int n0 = it * 64;
            #pragma unroll
            for (int p = 0; p < 4; ++p) {
                const int row = (w * 4 + p) * 8 + grow;
                async16(hyp16 + (size_t)(t0 + row) * BN + b * NDIM + n0 + gkq * 8,
                        &sA[(w * 4 + p) * 512]);
                async16(W16 + (size_t)(kblk * 128 + row) * NDIM + n0 + gkq * 8,
                        &sW[(w * 4 + p) * 512]);
            }
            __syncthreads();   // drains vmcnt before barrier -> fills visible

            #pragma unroll
            for (int kk = 0; kk < 2; ++kk) {
                const int swz = kk ? swz1 : swz0;
                bf16x8 af[4];
                #pragma unroll
                for (int mi = 0; mi < 4; ++mi) {
                    int mrow = wt * 64 + mi * 16 + lm;
                    af[mi] = *(const bf16x8*)&sA[mrow * 64 + swz];
                }
                #pragma unroll
                for (int ni = 0; ni < 4; ++ni) {
                    int nrow = wkk * 64 + ni * 16 + lm;
                    bf16x8 bfr = *(const bf16x8*)&sW[nrow * 64 + swz];
                    #pragma unroll
                    for (int mi = 0; mi < 4; ++mi)
                        acc[mi][ni] = __builtin_amdgcn_mfma_f32_16x16x32_bf16(
                            af[mi], bfr, acc[mi][ni], 0, 0, 0);
                }
            }
            __syncthreads();
        }

        // epilogue: tanh + fold g. D layout: col=lm (kcol), row=lq*4+r (t)
        #pragma unroll
        for (int ni = 0; ni < 4; ++ni) {
            int kc = kblk * 128 + wkk * 64 + ni * 16 + lm;
            float wbv = ldf(W_b, kc, isf32);
            float gg  = g[(size_t)b * N2DIM + kc];
            #pragma unroll
            for (int mi = 0; mi < 4; ++mi)
                #pragma unroll
                for (int r = 0; r < 4; ++r) {
                    float v = tanh_fast(acc[mi][ni][r] + wbv);
                    scoreAcc[mi][r] += v * gg;
                }
        }
    }

    #pragma unroll
    for (int mi = 0; mi < 4; ++mi)
        #pragma unroll
        for (int r = 0; r < 4; ++r) {
            float s = scoreAcc[mi][r];
            s += __shfl_xor(s, 1, 64);
            s += __shfl_xor(s, 2, 64);
            s += __shfl_xor(s, 4, 64);
            s += __shfl_xor(s, 8, 64);
            if (lm == 0) sRed[wkk][wt * 64 + mi * 16 + lq * 4 + r] = s;
        }
    __syncthreads();
    if (tid < 128) {
        score[(size_t)b * TDIM + t0 + tid] = sRed[0][tid] + sRed[1][tid];
    }
}

// Shared: softmax over T. grid 32, block 256.
__global__ __launch_bounds__(256) void k_softmax(const float* __restrict__ score,
                                                 float* __restrict__ a) {
    __shared__ float red[8];
    int b = blockIdx.x;
    int tid = threadIdx.x;
    int w = tid >> 6, l = tid & 63;
    const float* s = score + (size_t)b * TDIM;
    float v[8];
    float mx = -1e30f;
    #pragma unroll
    for (int i = 0; i < 8; ++i) { v[i] = s[tid + i * 256]; mx = fmaxf(mx, v[i]); }
    #pragma unroll
    for (int off = 32; off > 0; off >>= 1) mx = fmaxf(mx, __shfl_xor(mx, off, 64));
    if (l == 0) red[w] = mx;
    __syncthreads();
    mx = fmaxf(fmaxf(red[0], red[1]), fmaxf(red[2], red[3]));
    float sum = 0.f;
    #pragma unroll
    for (int i = 0; i < 8; ++i) { v[i] = __expf(v[i] - mx); sum += v[i]; }
    #pragma unroll
    for (int off = 32; off > 0; off >>= 1) sum += __shfl_xor(sum, off, 64);
    if (l == 0) red[4 + w] = sum;
    __syncthreads();
    sum = red[4] + red[5] + red[6] + red[7];
    float inv = 1.0f / sum;
    float* ap = a + (size_t)b * TDIM;
    #pragma unroll
    for (int i = 0; i < 8; ++i) ap[tid + i * 256] = v[i] * inv;
}

// P5: weighted partial sums from bf16 hyp16. grid (16,16), 8 cols/thread.
__global__ __launch_bounds__(256) void k_wsum_part(const unsigned short* __restrict__ hyp16,
                                                   const float* __restrict__ a,
                                                   float* __restrict__ part) {
    const int col8 = (blockIdx.x * 256 + threadIdx.x) * 8;
    const int tc   = blockIdx.y;
    const int b    = col8 >> 10;
    const float* av = a + (size_t)b * TDIM + tc * 128;
    const uint4* src = (const uint4*)(hyp16 + (size_t)(tc * 128) * BN + col8);
    float acc[8] = {0.f,0.f,0.f,0.f,0.f,0.f,0.f,0.f};
    #pragma unroll 4
    for (int tt = 0; tt < 128; ++tt) {
        float wgt = av[tt];
        uint4 u = src[(size_t)tt * (BN / 8)];
        float f[8]; unpack8(u, f);
        #pragma unroll
        for (int j = 0; j < 8; ++j) acc[j] += wgt * f[j];
    }
    float* dst = part + (size_t)tc * BN + col8;
    #pragma unroll
    for (int j = 0; j < 8; ++j) dst[j] = acc[j];
}

// P6: reduce 16 partials -> out (dtype per detect). grid 32, block 256.
__global__ __launch_bounds__(256) void k_reduce_out(const float* __restrict__ part,
                                                    const void* __restrict__ wb,
                                                    void* __restrict__ out) {
    const int isf32 = detect_f32(wb);
    int i4 = (blockIdx.x * 256 + threadIdx.x) * 4;
    float4 s = { 0.f, 0.f, 0.f, 0.f };
    #pragma unroll
    for (int c = 0; c < 16; ++c) {
        float4 v = *(const float4*)(part + (size_t)c * BN + i4);
        s.x += v.x; s.y += v.y; s.z += v.z; s.w += v.w;
    }
    if (isf32) {
        *(float4*)((float*)out + i4) = s;
    } else {
        ushort4 u = { f2bf(s.x), f2bf(s.y), f2bf(s.z), f2bf(s.w) };
        *(ushort4*)((unsigned short*)out + i4) = u;
    }
}

// ===========================================================================
// FALLBACK PATH (round-3 proven kernels; used only when ws is too small)
// ===========================================================================
__global__ __launch_bounds__(256) void k_mean_fb(const void* __restrict__ hyp,
                                                 const void* __restrict__ wb,
                                                 float* __restrict__ m) {
    const int isf32 = detect_f32(wb);
    int i = blockIdx.x * 256 + threadIdx.x;
    float s = 0.f;
    if (isf32) {
        const float* h = (const float*)hyp;
        #pragma unroll 8
        for (int t = 0; t < TDIM; ++t) s += h[(size_t)t * BN + i];
    } else {
        const unsigned short* h = (const unsigned short*)hyp;
        #pragma unroll 8
        for (int t = 0; t < TDIM; ++t) s += bf2f(h[(size_t)t * BN + i]);
    }
    m[i] = s * (1.0f / (float)TDIM);
}

__global__ __launch_bounds__(256) void k_score_fb(const void* __restrict__ hyp,
                                                  const void* __restrict__ W_w,
                                                  const void* __restrict__ W_b,
                                                  const float* __restrict__ g,
                                                  float* __restrict__ score) {
    __shared__ __align__(16) unsigned short sA[128 * LDSP];
    __shared__ __align__(16) unsigned short sW[128 * LDSP];
    __shared__ float sRed[2][128];

    const int isf32 = detect_f32(W_b);
    const int tid = threadIdx.x;
    const int l   = tid & 63;
    const int w   = tid >> 6;
    const int wt  = w & 1;
    const int wkk = w >> 1;
    const int lm  = l & 15;
    const int lq  = l >> 4;
    const int b   = blockIdx.y;
    const int t0  = blockIdx.x * 128;

    float scoreAcc[4][4];
    #pragma unroll
    for (int mi = 0; mi < 4; ++mi)
        #pragma unroll
        for (int r = 0; r < 4; ++r) scoreAcc[mi][r] = 0.f;

    for (int kblk = 0; kblk < 4; ++kblk) {
        f32x4 acc[4][4];
        #pragma unroll
        for (int mi = 0; mi < 4; ++mi)
            #pragma unroll
            for (int ni = 0; ni < 4; ++ni) {
                f32x4 z = {0.f, 0.f, 0.f, 0.f};
                acc[mi][ni] = z;
            }
        for (int it = 0; it < 16; ++it) {
            const int n0 = it * 64;
            #pragma unroll
            for (int p = 0; p < 4; ++p) {
                int ch  = p * 256 + tid;
                int row = ch >> 3;
                int pos = ch & 7;
                size_t offA = (size_t)(t0 + row) * BN + b * NDIM + n0 + pos * 8;
                size_t offW = (size_t)(kblk * 128 + row) * NDIM + n0 + pos * 8;
                uint4 va, vw;
                if (isf32) {
                    const float4* fa = (const float4*)((const float*)hyp + offA);
                    float4 a0 = fa[0], a1 = fa[1];
                    va.x = f2bf(a0.x) | ((unsigned)f2bf(a0.y) << 16);
                    va.y = f2bf(a0.z) | ((unsigned)f2bf(a0.w) << 16);
                    va.z = f2bf(a1.x) | ((unsigned)f2bf(a1.y) << 16);
                    va.w = f2bf(a1.z) | ((unsigned)f2bf(a1.w) << 16);
                    const float4* fw = (const float4*)((const float*)W_w + offW);
                    float4 w0 = fw[0], w1 = fw[1];
                    vw.x = f2bf(w0.x) | ((unsigned)f2bf(w0.y) << 16);
                    vw.y = f2bf(w0.z) | ((unsigned)f2bf(w0.w) << 16);
                    vw.z = f2bf(w1.x) | ((unsigned)f2bf(w1.y) << 16);
                    vw.w = f2bf(w1.z) | ((unsigned)f2bf(w1.w) << 16);
                } else {
                    va = *(const uint4*)((const unsigned short*)hyp + offA);
                    vw = *(const uint4*)((const unsigned short*)W_w + offW);
                }
                *(uint4*)&sA[row * LDSP + pos * 8] = va;
                *(uint4*)&sW[row * LDSP + pos * 8] = vw;
            }
            __syncthreads();
            #pragma unroll
            for (int kk = 0; kk < 2; ++kk) {
                const int koff = kk * 32 + lq * 8;
                bf16x8 af[4];
                #pragma unroll
                for (int mi = 0; mi < 4; ++mi) {
                    int mrow = wt * 64 + mi * 16 + lm;
                    af[mi] = *(const bf16x8*)&sA[mrow * LDSP + koff];
                }
                #pragma unroll
                for (int ni = 0; ni < 4; ++ni) {
                    int nrow = wkk * 64 + ni * 16 + lm;
                    bf16x8 bfr = *(const bf16x8*)&sW[nrow * LDSP + koff];
                    #pragma unroll
                    for (int mi = 0; mi < 4; ++mi)
                        acc[mi][ni] = __builtin_amdgcn_mfma_f32_16x16x32_bf16(
                            af[mi], bfr, acc[mi][ni], 0, 0, 0);
                }
            }
            __syncthreads();
        }
        #pragma unroll
        for (int ni = 0; ni < 4; ++ni) {
            int kc = kblk * 128 + wkk * 64 + ni * 16 + lm;
            float wbv = ldf(W_b, kc, isf32);
            float gg  = g[(size_t)b * N2DIM + kc];
            #pragma unroll
            for (int mi = 0; mi < 4; ++mi)
                #pragma unroll
                for (int r = 0; r < 4; ++r) {
                    float v = tanh_fast(acc[mi][ni][r] + wbv);
                    scoreAcc[mi][r] += v * gg;
                }
        }
    }
    #pragma unroll
    for (int mi = 0; mi < 4; ++mi)
        #pragma unroll
        for (int r = 0; r < 4; ++r) {
            float s = scoreAcc[mi][r];
            s += __shfl_xor(s, 1, 64);
            s += __shfl_xor(s, 2, 64);
            s += __shfl_xor(s, 4, 64);
            s += __shfl_xor(s, 8, 64);
            if (lm == 0) sRed[wkk][wt * 64 + mi * 16 + lq * 4 + r] = s;
        }
    __syncthreads();
    if (tid < 128) {
        score[(size_t)b * TDIM + t0 + tid] = sRed[0][tid] + sRed[1][tid];
    }
}

__global__ __launch_bounds__(256) void k_wsum_fb(const void* __restrict__ hyp,
                                                 const float* __restrict__ a,
                                                 const void* __restrict__ wb,
                                                 void* __restrict__ out) {
    const int isf32 = detect_f32(wb);
    int i = blockIdx.x * 256 + threadIdx.x;
    int b = i >> 10;
    const float* av = a + (size_t)b * TDIM;
    float s = 0.f;
    if (isf32) {
        const float* h = (const float*)hyp;
        #pragma unroll 8
        for (int t = 0; t < TDIM; ++t) s += av[t] * h[(size_t)t * BN + i];
    } else {
        const unsigned short* h = (const unsigned short*)hyp;
        #pragma unroll 8
        for (int t = 0; t < TDIM; ++t) s += av[t] * bf2f(h[(size_t)t * BN + i]);
    }
    if (isf32) ((float*)out)[i] = s;
    else       ((unsigned short*)out)[i] = f2bf(s);
}

extern "C" void kernel_launch(void* const* d_in, const int* in_sizes, int n_in,
                              void* d_out, int out_size, void* d_ws, size_t ws_size,
                              hipStream_t stream) {
    const void* hyp  = d_in[0];
    const void* W_w  = d_in[1];
    const void* W_b  = d_in[2];
    const void* Wm_w = d_in[3];
    const void* Wm_b = d_in[4];
    const void* Wh_w = d_in[5];
    // d_in[6] (Wh_b) is softmax-invariant -> unused.

    float* ws    = (float*)d_ws;
    float* m     = ws;                        // 32768 f
    float* g     = m + BN;                    // 16384 f
    float* score = g + BDIM * N2DIM;          // 65536 f
    float* a     = score + BDIM * TDIM;       // 65536 f
    float* part  = a + BDIM * TDIM;           // 524288 f
    unsigned short* W16   = (unsigned short*)(part + 16 * BN);  // 524288 shorts
    unsigned short* hyp16 = W16 + (size_t)N2DIM * NDIM;         // 67108864 shorts
    const size_t need = 138084352ull;  // bytes through end of hyp16

    if (ws_size >= need) {
        k_mean_cvt  <<<dim3(32, 16), 256, 0, stream>>>(hyp, W_b, hyp16, part);
        k_reduce_mean<<<dim3(32),    256, 0, stream>>>(part, m);
        k_cvtW      <<<dim3(512),    256, 0, stream>>>(W_w, W_b, W16);
        k_g         <<<dim3(4096),   256, 0, stream>>>(m, Wm_w, Wm_b, Wh_w, W_b, g);
        k_score     <<<dim3(16, 32), 256, 0, stream>>>(hyp16, W16, W_b, g, score);
        k_softmax   <<<dim3(32),     256, 0, stream>>>(score, a);
        k_wsum_part <<<dim3(16, 16), 256, 0, stream>>>(hyp16, a, part);
        k_reduce_out<<<dim3(32),     256, 0, stream>>>(part, W_b, d_out);
    } else {
        k_mean_fb   <<<dim3(128),    256, 0, stream>>>(hyp, W_b, m);
        k_g         <<<dim3(4096),   256, 0, stream>>>(m, Wm_w, Wm_b, Wh_w, W_b, g);
        k_score_fb  <<<dim3(16, 32), 256, 0, stream>>>(hyp, W_w, W_b, g, score);
        k_softmax   <<<dim3(32),     256, 0, stream>>>(score, a);
        k_wsum_fb   <<<dim3(128),    256, 0, stream>>>(hyp, a, W_b, d_out);
    }
}

// Round 5
// 556.559 us; speedup vs baseline: 1.8211x; 1.0136x over previous
//
#include <hip/hip_runtime.h>
#include <hip/hip_bf16.h>

#define TDIM 2048
#define BDIM 32
#define NDIM 1024
#define N2DIM 512
#define BN (BDIM * NDIM)   // 32768
#define LDSP 72            // fallback padded LDS row stride (shorts)
#define NPART 64           // t-chunks for streaming partials (32 t each)

typedef float f32x4 __attribute__((ext_vector_type(4)));
typedef __bf16 bf16x8 __attribute__((ext_vector_type(8)));

__device__ __forceinline__ float bf2f(unsigned int u) {
    union { unsigned int i; float f; } c;
    c.i = (u & 0xffffu) << 16;
    return c.f;
}

__device__ __forceinline__ unsigned short f2bf(float f) {
    union { float f; unsigned int i; } c;
    c.f = f;
    unsigned int i = c.i;
    unsigned int r = (i >> 16) & 1u;
    i += 0x7fffu + r;          // round-to-nearest-even
    return (unsigned short)(i >> 16);
}

// Runtime dtype detector (evidence says fp32; guard kept).
__device__ __forceinline__ int detect_f32(const void* wb) {
    const unsigned short* p = (const unsigned short*)wb;
    int cnt = 0;
    #pragma unroll
    for (int i = 0; i < 64; ++i) cnt += ((p[i] & 0x7fffu) <= 0x3D00u) ? 1 : 0;
    return cnt != 64;
}

__device__ __forceinline__ float ldf(const void* p, size_t i, int isf32) {
    if (isf32) return ((const float*)p)[i];
    return bf2f(((const unsigned short*)p)[i]);
}

__device__ __forceinline__ float tanh_fast(float x) {
    float e = __expf(2.0f * x);
    return 1.0f - 2.0f / (e + 1.0f);
}

__device__ __forceinline__ void unpack8(uint4 u, float* f) {
    f[0] = bf2f(u.x); f[1] = bf2f(u.x >> 16);
    f[2] = bf2f(u.y); f[3] = bf2f(u.y >> 16);
    f[4] = bf2f(u.z); f[5] = bf2f(u.z >> 16);
    f[6] = bf2f(u.w); f[7] = bf2f(u.w >> 16);
}

__device__ __forceinline__ void async16(const void* g, void* l) {
    __builtin_amdgcn_global_load_lds(
        (const __attribute__((address_space(1))) void*)g,
        (__attribute__((address_space(3))) void*)l, 16, 0, 0);
}

// ===========================================================================
// PRIMARY PATH
// ===========================================================================

// P1: partial column sums + bf16 conversion. grid (32, NPART), block 256.
// Thread owns 4 cols; loops 32 t of chunk tc.
__global__ __launch_bounds__(256) void k_mean_cvt(const void* __restrict__ hyp,
                                                  const void* __restrict__ wb,
                                                  unsigned short* __restrict__ hyp16,
                                                  float* __restrict__ part) {
    const int isf32 = detect_f32(wb);
    const int col4 = (blockIdx.x * 256 + threadIdx.x) * 4;
    const int tc   = blockIdx.y;
    float a0 = 0.f, a1 = 0.f, a2 = 0.f, a3 = 0.f;
    if (isf32) {
        const float* h = (const float*)hyp + (size_t)(tc * 32) * BN + col4;
        unsigned short* o = hyp16 + (size_t)(tc * 32) * BN + col4;
        #pragma unroll 8
        for (int tt = 0; tt < 32; ++tt) {
            float4 v = *(const float4*)(h + (size_t)tt * BN);
            a0 += v.x; a1 += v.y; a2 += v.z; a3 += v.w;
            ushort4 u = { f2bf(v.x), f2bf(v.y), f2bf(v.z), f2bf(v.w) };
            *(ushort4*)(o + (size_t)tt * BN) = u;
        }
    } else {
        const unsigned short* h = (const unsigned short*)hyp + (size_t)(tc * 32) * BN + col4;
        unsigned short* o = hyp16 + (size_t)(tc * 32) * BN + col4;
        #pragma unroll 8
        for (int tt = 0; tt < 32; ++tt) {
            ushort4 u = *(const ushort4*)(h + (size_t)tt * BN);
            *(ushort4*)(o + (size_t)tt * BN) = u;
            a0 += bf2f(u.x); a1 += bf2f(u.y); a2 += bf2f(u.z); a3 += bf2f(u.w);
        }
    }
    float4 r = { a0, a1, a2, a3 };
    *(float4*)(part + (size_t)tc * BN + col4) = r;
}

// P2 (fused): blocks 0..511 convert W_w -> bf16; blocks 512..543 reduce mean.
__global__ __launch_bounds__(256) void k_prep(const void* __restrict__ W_w,
                                              const void* __restrict__ wb,
                                              const float* __restrict__ part,
                                              unsigned short* __restrict__ W16,
                                              float* __restrict__ m) {
    const int isf32 = detect_f32(wb);
    if (blockIdx.x < 512) {
        int i4 = (blockIdx.x * 256 + threadIdx.x) * 4;
        if (isf32) {
            float4 v = *(const float4*)((const float*)W_w + i4);
            ushort4 u = { f2bf(v.x), f2bf(v.y), f2bf(v.z), f2bf(v.w) };
            *(ushort4*)(W16 + i4) = u;
        } else {
            *(ushort4*)(W16 + i4) = *(const ushort4*)((const unsigned short*)W_w + i4);
        }
    } else {
        int i4 = ((blockIdx.x - 512) * 256 + threadIdx.x) * 4;
        float4 s = { 0.f, 0.f, 0.f, 0.f };
        #pragma unroll
        for (int c = 0; c < NPART; ++c) {
            float4 v = *(const float4*)(part + (size_t)c * BN + i4);
            s.x += v.x; s.y += v.y; s.z += v.z; s.w += v.w;
        }
        float k = 1.0f / (float)TDIM;
        float4 r = { s.x * k, s.y * k, s.z * k, s.w * k };
        *(float4*)(m + i4) = r;
    }
}

// P3: g[b][k] = tanh(m[b]·Wm_w[k] + Wm_b[k]) * Wh_w[k]. grid 4096, blk 256.
__global__ __launch_bounds__(256) void k_g(const float* __restrict__ m,
                                           const void* __restrict__ Wm_w,
                                           const void* __restrict__ Wm_b,
                                           const void* __restrict__ Wh_w,
                                           const void* __restrict__ wb,
                                           float* __restrict__ g) {
    const int isf32 = detect_f32(wb);
    int wid  = (blockIdx.x * 256 + threadIdx.x) >> 6;
    int lane = threadIdx.x & 63;
    int b = wid >> 9;
    int k = wid & 511;
    const float* mr = m + (size_t)b * NDIM;
    float s = 0.f;
    if (isf32) {
        const float* wr = (const float*)Wm_w + (size_t)k * NDIM;
        #pragma unroll
        for (int i = 0; i < 4; ++i) {
            int idx = (lane + i * 64) * 4;
            float4 mv = *(const float4*)(mr + idx);
            float4 wv = *(const float4*)(wr + idx);
            s += mv.x * wv.x + mv.y * wv.y + mv.z * wv.z + mv.w * wv.w;
        }
    } else {
        const unsigned short* wr = (const unsigned short*)Wm_w + (size_t)k * NDIM;
        #pragma unroll
        for (int i = 0; i < 4; ++i) {
            int idx = (lane + i * 64) * 4;
            float4 mv = *(const float4*)(mr + idx);
            ushort4 wv = *(const ushort4*)(wr + idx);
            s += mv.x * bf2f(wv.x) + mv.y * bf2f(wv.y)
               + mv.z * bf2f(wv.z) + mv.w * bf2f(wv.w);
        }
    }
    #pragma unroll
    for (int off = 32; off > 0; off >>= 1) s += __shfl_down(s, off, 64);
    if (lane == 0) {
        float v = tanh_fast(s + ldf(Wm_b, k, isf32));
        g[(size_t)b * N2DIM + k] = v * ldf(Wh_w, k, isf32);
    }
}

// ---------------------------------------------------------------------------
// P4: fused GEMM+tanh+weighted-k-reduce, kblk split across grid.z.
// Tile [128 t x 128 kcol], 4 waves 2x2, XOR-swizzled frag-order LDS,
// global_load_lds width-16. grid (16, 32, 4), block 256.
// Writes partial score: sp[(kblk*BDIM + b)*TDIM + t].
// ---------------------------------------------------------------------------
__global__ __launch_bounds__(256) void k_score(const unsigned short* __restrict__ hyp16,
                                               const unsigned short* __restrict__ W16,
                                               const void* __restrict__ W_b,
                                               const float* __restrict__ g,
                                               float* __restrict__ sp) {
    __shared__ __align__(16) unsigned short sA[128 * 64];  // 16 KB
    __shared__ __align__(16) unsigned short sW[128 * 64];  // 16 KB
    __shared__ float sRed[2][128];

    const int isf32 = detect_f32(W_b);
    const int tid = threadIdx.x;
    const int l   = tid & 63;
    const int w   = tid >> 6;
    const int wt  = w & 1;
    const int wkk = w >> 1;
    const int lm  = l & 15;
    const int lq  = l >> 4;
    const int b   = blockIdx.y;
    const int t0  = blockIdx.x * 128;
    const int kblk = blockIdx.z;

    const int grow = l >> 3;
    const int gkq  = (l & 7) ^ grow;
    const int swz0 = ((lq)     ^ (lm & 7)) * 8;
    const int swz1 = ((4 + lq) ^ (lm & 7)) * 8;

    f32x4 acc[4][4];
    #pragma unroll
    for (int mi = 0; mi < 4; ++mi)
        #pragma unroll
        for (int ni = 0; ni < 4; ++ni) {
            f32x4 z = {0.f, 0.f, 0.f, 0.f};
            acc[mi][ni] = z;
        }

    for (int it = 0; it < 16; ++it) {
        const int n0 = it * 64;
        #pragma unroll
        for (int p = 0; p < 4; ++p) {
            const int row = (w * 4 + p) * 8 + grow;
            async16(hyp16 + (size_t)(t0 + row) * BN + b * NDIM + n0 + gkq * 8,
                    &sA[(w * 4 + p) * 512]);
            async16(W16 + (size_t)(kblk * 128 + row) * NDIM + n0 + gkq * 8,
                    &sW[(w * 4 + p) * 512]);
        }
        __syncthreads();

        #pragma unroll
        for (int kk = 0; kk < 2; ++kk) {
            const int swz = kk ? swz1 : swz0;
            bf16x8 af[4];
            #pragma unroll
            for (int mi = 0; mi < 4; ++mi) {
                int mrow = wt * 64 + mi * 16 + lm;
                af[mi] = *(const bf16x8*)&sA[mrow * 64 + swz];
            }
            #pragma unroll
            for (int ni = 0; ni < 4; ++ni) {
                int nrow = wkk * 64 + ni * 16 + lm;
                bf16x8 bfr = *(const bf16x8*)&sW[nrow * 64 + swz];
                #pragma unroll
                for (int mi = 0; mi < 4; ++mi)
                    acc[mi][ni] = __builtin_amdgcn_mfma_f32_16x16x32_bf16(
                        af[mi], bfr, acc[mi][ni], 0, 0, 0);
            }
        }
        __syncthreads();
    }

    // epilogue: tanh + fold g. D layout: col=lm (kcol), row=lq*4+r (t)
    float scoreAcc[4][4];
    #pragma unroll
    for (int mi = 0; mi < 4; ++mi)
        #pragma unroll
        for (int r = 0; r < 4; ++r) scoreAcc[mi][r] = 0.f;
    #pragma unroll
    for (int ni = 0; ni < 4; ++ni) {
        int kc = kblk * 128 + wkk * 64 + ni * 16 + lm;
        float wbv = ldf(W_b, kc, isf32);
        float gg  = g[(size_t)b * N2DIM + kc];
        #pragma unroll
        for (int mi = 0; mi < 4; ++mi)
            #pragma unroll
            for (int r = 0; r < 4; ++r) {
                float v = tanh_fast(acc[mi][ni][r] + wbv);
                scoreAcc[mi][r] += v * gg;
            }
    }

    #pragma unroll
    for (int mi = 0; mi < 4; ++mi)
        #pragma unroll
        for (int r = 0; r < 4; ++r) {
            float s = scoreAcc[mi][r];
            s += __shfl_xor(s, 1, 64);
            s += __shfl_xor(s, 2, 64);
            s += __shfl_xor(s, 4, 64);
            s += __shfl_xor(s, 8, 64);
            if (lm == 0) sRed[wkk][wt * 64 + mi * 16 + lq * 4 + r] = s;
        }
    __syncthreads();
    if (tid < 128) {
        sp[(size_t)(kblk * BDIM + b) * TDIM + t0 + tid] = sRed[0][tid] + sRed[1][tid];
    }
}

// P5: softmax over T (summing 4 kblk partials). grid 32, block 256.
__global__ __launch_bounds__(256) void k_softmax(const float* __restrict__ sp,
                                                 float* __restrict__ a) {
    __shared__ float red[8];
    int b = blockIdx.x;
    int tid = threadIdx.x;
    int w = tid >> 6, l = tid & 63;
    float v[8];
    float mx = -1e30f;
    #pragma unroll
    for (int i = 0; i < 8; ++i) {
        int t = tid + i * 256;
        float s = sp[(size_t)(0 * BDIM + b) * TDIM + t]
                + sp[(size_t)(1 * BDIM + b) * TDIM + t]
                + sp[(size_t)(2 * BDIM + b) * TDIM + t]
                + sp[(size_t)(3 * BDIM + b) * TDIM + t];
        v[i] = s; mx = fmaxf(mx, s);
    }
    #pragma unroll
    for (int off = 32; off > 0; off >>= 1) mx = fmaxf(mx, __shfl_xor(mx, off, 64));
    if (l == 0) red[w] = mx;
    __syncthreads();
    mx = fmaxf(fmaxf(red[0], red[1]), fmaxf(red[2], red[3]));
    float sum = 0.f;
    #pragma unroll
    for (int i = 0; i < 8; ++i) { v[i] = __expf(v[i] - mx); sum += v[i]; }
    #pragma unroll
    for (int off = 32; off > 0; off >>= 1) sum += __shfl_xor(sum, off, 64);
    if (l == 0) red[4 + w] = sum;
    __syncthreads();
    sum = red[4] + red[5] + red[6] + red[7];
    float inv = 1.0f / sum;
    float* ap = a + (size_t)b * TDIM;
    #pragma unroll
    for (int i = 0; i < 8; ++i) ap[tid + i * 256] = v[i] * inv;
}

// P6: weighted partial sums from hyp16. grid (16, NPART), 8 cols/thread.
__global__ __launch_bounds__(256) void k_wsum_part(const unsigned short* __restrict__ hyp16,
                                                   const float* __restrict__ a,
                                                   float* __restrict__ part) {
    const int col8 = (blockIdx.x * 256 + threadIdx.x) * 8;
    const int tc   = blockIdx.y;
    const int b    = col8 >> 10;
    const float* av = a + (size_t)b * TDIM + tc * 32;
    const uint4* src = (const uint4*)(hyp16 + (size_t)(tc * 32) * BN + col8);
    float acc[8] = {0.f,0.f,0.f,0.f,0.f,0.f,0.f,0.f};
    #pragma unroll 8
    for (int tt = 0; tt < 32; ++tt) {
        float wgt = av[tt];
        uint4 u = src[(size_t)tt * (BN / 8)];
        float f[8]; unpack8(u, f);
        #pragma unroll
        for (int j = 0; j < 8; ++j) acc[j] += wgt * f[j];
    }
    float* dst = part + (size_t)tc * BN + col8;
    #pragma unroll
    for (int j = 0; j < 8; ++j) dst[j] = acc[j];
}

// P7: reduce NPART partials -> out. grid 32, block 256.
__global__ __launch_bounds__(256) void k_reduce_out(const float* __restrict__ part,
                                                    const void* __restrict__ wb,
                                                    void* __restrict__ out) {
    const int isf32 = detect_f32(wb);
    int i4 = (blockIdx.x * 256 + threadIdx.x) * 4;
    float4 s = { 0.f, 0.f, 0.f, 0.f };
    #pragma unroll
    for (int c = 0; c < NPART; ++c) {
        float4 v = *(const float4*)(part + (size_t)c * BN + i4);
        s.x += v.x; s.y += v.y; s.z += v.z; s.w += v.w;
    }
    if (isf32) {
        *(float4*)((float*)out + i4) = s;
    } else {
        ushort4 u = { f2bf(s.x), f2bf(s.y), f2bf(s.z), f2bf(s.w) };
        *(ushort4*)((unsigned short*)out + i4) = u;
    }
}

// ===========================================================================
// FALLBACK PATH (round-3 proven kernels; used only when ws is too small)
// ===========================================================================
__global__ __launch_bounds__(256) void k_mean_fb(const void* __restrict__ hyp,
                                                 const void* __restrict__ wb,
                                                 float* __restrict__ m) {
    const int isf32 = detect_f32(wb);
    int i = blockIdx.x * 256 + threadIdx.x;
    float s = 0.f;
    if (isf32) {
        const float* h = (const float*)hyp;
        #pragma unroll 8
        for (int t = 0; t < TDIM; ++t) s += h[(size_t)t * BN + i];
    } else {
        const unsigned short* h = (const unsigned short*)hyp;
        #pragma unroll 8
        for (int t = 0; t < TDIM; ++t) s += bf2f(h[(size_t)t * BN + i]);
    }
    m[i] = s * (1.0f / (float)TDIM);
}

__global__ __launch_bounds__(256) void k_score_fb(const void* __restrict__ hyp,
                                                  const void* __restrict__ W_w,
                                                  const void* __restrict__ W_b,
                                                  const float* __restrict__ g,
                                                  float* __restrict__ score) {
    __shared__ __align__(16) unsigned short sA[128 * LDSP];
    __shared__ __align__(16) unsigned short sW[128 * LDSP];
    __shared__ float sRed[2][128];

    const int isf32 = detect_f32(W_b);
    const int tid = threadIdx.x;
    const int l   = tid & 63;
    const int w   = tid >> 6;
    const int wt  = w & 1;
    const int wkk = w >> 1;
    const int lm  = l & 15;
    const int lq  = l >> 4;
    const int b   = blockIdx.y;
    const int t0  = blockIdx.x * 128;

    float scoreAcc[4][4];
    #pragma unroll
    for (int mi = 0; mi < 4; ++mi)
        #pragma unroll
        for (int r = 0; r < 4; ++r) scoreAcc[mi][r] = 0.f;

    for (int kblk = 0; kblk < 4; ++kblk) {
        f32x4 acc[4][4];
        #pragma unroll
        for (int mi = 0; mi < 4; ++mi)
            #pragma unroll
            for (int ni = 0; ni < 4; ++ni) {
                f32x4 z = {0.f, 0.f, 0.f, 0.f};
                acc[mi][ni] = z;
            }
        for (int it = 0; it < 16; ++it) {
            const int n0 = it * 64;
            #pragma unroll
            for (int p = 0; p < 4; ++p) {
                int ch  = p * 256 + tid;
                int row = ch >> 3;
                int pos = ch & 7;
                size_t offA = (size_t)(t0 + row) * BN + b * NDIM + n0 + pos * 8;
                size_t offW = (size_t)(kblk * 128 + row) * NDIM + n0 + pos * 8;
                uint4 va, vw;
                if (isf32) {
                    const float4* fa = (const float4*)((const float*)hyp + offA);
                    float4 a0 = fa[0], a1 = fa[1];
                    va.x = f2bf(a0.x) | ((unsigned)f2bf(a0.y) << 16);
                    va.y = f2bf(a0.z) | ((unsigned)f2bf(a0.w) << 16);
                    va.z = f2bf(a1.x) | ((unsigned)f2bf(a1.y) << 16);
                    va.w = f2bf(a1.z) | ((unsigned)f2bf(a1.w) << 16);
                    const float4* fw = (const float4*)((const float*)W_w + offW);
                    float4 w0 = fw[0], w1 = fw[1];
                    vw.x = f2bf(w0.x) | ((unsigned)f2bf(w0.y) << 16);
                    vw.y = f2bf(w0.z) | ((unsigned)f2bf(w0.w) << 16);
                    vw.z = f2bf(w1.x) | ((unsigned)f2bf(w1.y) << 16);
                    vw.w = f2bf(w1.z) | ((unsigned)f2bf(w1.w) << 16);
                } else {
                    va = *(const uint4*)((const unsigned short*)hyp + offA);
                    vw = *(const uint4*)((const unsigned short*)W_w + offW);
                }
                *(uint4*)&sA[row * LDSP + pos * 8] = va;
                *(uint4*)&sW[row * LDSP + pos * 8] = vw;
            }
            __syncthreads();
            #pragma unroll
            for (int kk = 0; kk < 2; ++kk) {
                const int koff = kk * 32 + lq * 8;
                bf16x8 af[4];
                #pragma unroll
                for (int mi = 0; mi < 4; ++mi) {
                    int mrow = wt * 64 + mi * 16 + lm;
                    af[mi] = *(const bf16x8*)&sA[mrow * LDSP + koff];
                }
                #pragma unroll
                for (int ni = 0; ni < 4; ++ni) {
                    int nrow = wkk * 64 + ni * 16 + lm;
                    bf16x8 bfr = *(const bf16x8*)&sW[nrow * LDSP + koff];
                    #pragma unroll
                    for (int mi = 0; mi < 4; ++mi)
                        acc[mi][ni] = __builtin_amdgcn_mfma_f32_16x16x32_bf16(
                            af[mi], bfr, acc[mi][ni], 0, 0, 0);
                }
            }
            __syncthreads();
        }
        #pragma unroll
        for (int ni = 0; ni < 4; ++ni) {
            int kc = kblk * 128 + wkk * 64 + ni * 16 + lm;
            float wbv = ldf(W_b, kc, isf32);
            float gg  = g[(size_t)b * N2DIM + kc];
            #pragma unroll
            for (int mi = 0; mi < 4; ++mi)
                #pragma unroll
                for (int r = 0; r < 4; ++r) {
                    float v = tanh_fast(acc[mi][ni][r] + wbv);
                    scoreAcc[mi][r] += v * gg;
                }
        }
    }
    #pragma unroll
    for (int mi = 0; mi < 4; ++mi)
        #pragma unroll
        for (int r = 0; r < 4; ++r) {
            float s = scoreAcc[mi][r];
            s += __shfl_xor(s, 1, 64);
            s += __shfl_xor(s, 2, 64);
            s += __shfl_xor(s, 4, 64);
            s += __shfl_xor(s, 8, 64);
            if (lm == 0) sRed[wkk][wt * 64 + mi * 16 + lq * 4 + r] = s;
        }
    __syncthreads();
    if (tid < 128) {
        score[(size_t)b * TDIM + t0 + tid] = sRed[0][tid] + sRed[1][tid];
    }
}

__global__ __launch_bounds__(256) void k_softmax_fb(const float* __restrict__ score,
                                                    float* __restrict__ a) {
    __shared__ float red[8];
    int b = blockIdx.x;
    int tid = threadIdx.x;
    int w = tid >> 6, l = tid & 63;
    const float* s = score + (size_t)b * TDIM;
    float v[8];
    float mx = -1e30f;
    #pragma unroll
    for (int i = 0; i < 8; ++i) { v[i] = s[tid + i * 256]; mx = fmaxf(mx, v[i]); }
    #pragma unroll
    for (int off = 32; off > 0; off >>= 1) mx = fmaxf(mx, __shfl_xor(mx, off, 64));
    if (l == 0) red[w] = mx;
    __syncthreads();
    mx = fmaxf(fmaxf(red[0], red[1]), fmaxf(red[2], red[3]));
    float sum = 0.f;
    #pragma unroll
    for (int i = 0; i < 8; ++i) { v[i] = __expf(v[i] - mx); sum += v[i]; }
    #pragma unroll
    for (int off = 32; off > 0; off >>= 1) sum += __shfl_xor(sum, off, 64);
    if (l == 0) red[4 + w] = sum;
    __syncthreads();
    sum = red[4] + red[5] + red[6] + red[7];
    float inv = 1.0f / sum;
    float* ap = a + (size_t)b * TDIM;
    #pragma unroll
    for (int i = 0; i < 8; ++i) ap[tid + i * 256] = v[i] * inv;
}

__global__ __launch_bounds__(256) void k_wsum_fb(const void* __restrict__ hyp,
                                                 const float* __restrict__ a,
                                                 const void* __restrict__ wb,
                                                 void* __restrict__ out) {
    const int isf32 = detect_f32(wb);
    int i = blockIdx.x * 256 + threadIdx.x;
    int b = i >> 10;
    const float* av = a + (size_t)b * TDIM;
    float s = 0.f;
    if (isf32) {
        const float* h = (const float*)hyp;
        #pragma unroll 8
        for (int t = 0; t < TDIM; ++t) s += av[t] * h[(size_t)t * BN + i];
    } else {
        const unsigned short* h = (const unsigned short*)hyp;
        #pragma unroll 8
        for (int t = 0; t < TDIM; ++t) s += av[t] * bf2f(h[(size_t)t * BN + i]);
    }
    if (isf32) ((float*)out)[i] = s;
    else       ((unsigned short*)out)[i] = f2bf(s);
}

extern "C" void kernel_launch(void* const* d_in, const int* in_sizes, int n_in,
                              void* d_out, int out_size, void* d_ws, size_t ws_size,
                              hipStream_t stream) {
    const void* hyp  = d_in[0];
    const void* W_w  = d_in[1];
    const void* W_b  = d_in[2];
    const void* Wm_w = d_in[3];
    const void* Wm_b = d_in[4];
    const void* Wh_w = d_in[5];
    // d_in[6] (Wh_b) is softmax-invariant -> unused.

    float* ws    = (float*)d_ws;
    float* m     = ws;                         // 32768 f
    float* g     = m + BN;                     // 16384 f
    float* sp    = g + BDIM * N2DIM;           // 4*32*2048 = 262144 f
    float* a     = sp + 4 * BDIM * TDIM;       // 65536 f
    float* part  = a + BDIM * TDIM;            // NPART*BN = 2097152 f
    unsigned short* W16   = (unsigned short*)(part + NPART * BN);  // 524288 sh
    unsigned short* hyp16 = W16 + (size_t)N2DIM * NDIM;            // 67108864 sh
    const size_t need = 145162240ull;

    if (ws_size >= need) {
        k_mean_cvt <<<dim3(32, NPART), 256, 0, stream>>>(hyp, W_b, hyp16, part);
        k_prep     <<<dim3(544),       256, 0, stream>>>(W_w, W_b, part, W16, m);
        k_g        <<<dim3(4096),      256, 0, stream>>>(m, Wm_w, Wm_b, Wh_w, W_b, g);
        k_score    <<<dim3(16, 32, 4), 256, 0, stream>>>(hyp16, W16, W_b, g, sp);
        k_softmax  <<<dim3(32),        256, 0, stream>>>(sp, a);
        k_wsum_part<<<dim3(16, NPART), 256, 0, stream>>>(hyp16, a, part);
        k_reduce_out<<<dim3(32),       256, 0, stream>>>(part, W_b, d_out);
    } else {
        float* score = sp;  // reuse slot
        k_mean_fb  <<<dim3(128),    256, 0, stream>>>(hyp, W_b, m);
        k_g        <<<dim3(4096),   256, 0, stream>>>(m, Wm_w, Wm_b, Wh_w, W_b, g);
        k_score_fb <<<dim3(16, 32), 256, 0, stream>>>(hyp, W_w, W_b, g, score);
        k_softmax_fb<<<dim3(32),    256, 0, stream>>>(score, a);
        k_wsum_fb  <<<dim3(128),    256, 0, stream>>>(hyp, a, W_b, d_out);
    }
}